// Round 1
// baseline (454.264 us; speedup 1.0000x reference)
//
#include <hip/hip_runtime.h>
#include <stdint.h>

#define S_LEN 2048
#define NH 16
#define NG 8
#define HDIM 128

typedef __bf16 bf16x8 __attribute__((ext_vector_type(8)));
typedef float f32x4 __attribute__((ext_vector_type(4)));

#define MFMA16(a, b, c) __builtin_amdgcn_mfma_f32_16x16x32_bf16((a), (b), (c), 0, 0, 0)

__device__ __forceinline__ uint16_t f2bf(float f) {
  union { float f; uint32_t u; } v; v.f = f;
  return (uint16_t)((v.u + 0x7fffu + ((v.u >> 16) & 1u)) >> 16);
}

__device__ __forceinline__ void gload16(const void* g, void* l) {
  __builtin_amdgcn_global_load_lds(
      (__attribute__((address_space(1))) const void*)g,
      (__attribute__((address_space(3))) void*)l, 16, 0, 0);
}

// ---------------- x -> bf16 ----------------
__global__ __launch_bounds__(256) void cvt_x_kernel(
    const float* __restrict__ x, uint16_t* __restrict__ xb, int n4) {
  int i = blockIdx.x * 256 + threadIdx.x;
  if (i >= n4) return;
  float4 v = ((const float4*)x)[i];
  ushort4 o;
  o.x = f2bf(v.x); o.y = f2bf(v.y); o.z = f2bf(v.z); o.w = f2bf(v.w);
  ((ushort4*)xb)[i] = o;
}

// ---------------- W[k][n] f32 -> dst[n][k] bf16 ----------------
__global__ __launch_bounds__(256) void trans_cvt_kernel(
    const float* __restrict__ src, uint16_t* __restrict__ dst, int K, int N) {
  __shared__ float T[32][33];
  int n0 = blockIdx.x * 32, k0 = blockIdx.y * 32;
  int tx = threadIdx.x & 31, ty = threadIdx.x >> 5;  // 32 x 8
  #pragma unroll
  for (int i = 0; i < 4; ++i)
    T[ty + i * 8][tx] = src[(size_t)(k0 + ty + i * 8) * N + n0 + tx];
  __syncthreads();
  #pragma unroll
  for (int i = 0; i < 4; ++i)
    dst[(size_t)(n0 + ty + i * 8) * K + k0 + tx] = f2bf(T[tx][ty + i * 8]);
}

// ---------------- C[M][N] f32 = A[M][K]bf16 @ BT[N][K]bf16 (m97 structure) ----------------
__global__ __launch_bounds__(256) void gemm_bt_kernel(
    const uint16_t* __restrict__ A, const uint16_t* __restrict__ BT,
    float* __restrict__ C, int M, int N, int K) {
  __shared__ uint8_t smem[32768];
  uint16_t* As = (uint16_t*)smem;            // [128][64]
  uint16_t* Bs = (uint16_t*)(smem + 16384);  // [128][64]
  const int tid = threadIdx.x, lane = tid & 63, wid = tid >> 6;
  const int l15 = lane & 15, l4 = lane >> 4;
  const int m0 = blockIdx.y * 128, n0 = blockIdx.x * 128;
  const int wm = (wid >> 1) * 64, wn = (wid & 1) * 64;
  const int s_row = lane >> 3, s_col = (lane & 7) * 8;  // 1KB chunk = 8 rows x 128B

  f32x4 acc[4][4];
  #pragma unroll
  for (int i = 0; i < 4; ++i)
    #pragma unroll
    for (int j = 0; j < 4; ++j) acc[i][j] = (f32x4){0.f, 0.f, 0.f, 0.f};

  for (int k0 = 0; k0 < K; k0 += 64) {
    #pragma unroll
    for (int i = 0; i < 4; ++i) {
      int chunk = wid * 4 + i;
      int row = chunk * 8 + s_row;
      gload16(A + (size_t)(m0 + row) * K + k0 + s_col, As + chunk * 512);
    }
    #pragma unroll
    for (int i = 0; i < 4; ++i) {
      int chunk = wid * 4 + i;
      int row = chunk * 8 + s_row;
      gload16(BT + (size_t)(n0 + row) * K + k0 + s_col, Bs + chunk * 512);
    }
    __syncthreads();
    #pragma unroll
    for (int kk = 0; kk < 2; ++kk) {
      bf16x8 af[4], bfr[4];
      #pragma unroll
      for (int mi = 0; mi < 4; ++mi)
        af[mi] = *(const bf16x8*)(As + (wm + mi * 16 + l15) * 64 + kk * 32 + l4 * 8);
      #pragma unroll
      for (int ni = 0; ni < 4; ++ni)
        bfr[ni] = *(const bf16x8*)(Bs + (wn + ni * 16 + l15) * 64 + kk * 32 + l4 * 8);
      #pragma unroll
      for (int mi = 0; mi < 4; ++mi)
        #pragma unroll
        for (int ni = 0; ni < 4; ++ni)
          acc[mi][ni] = MFMA16(af[mi], bfr[ni], acc[mi][ni]);
    }
    __syncthreads();
  }
  #pragma unroll
  for (int mi = 0; mi < 4; ++mi)
    #pragma unroll
    for (int ni = 0; ni < 4; ++ni) {
      float* dst = C + (size_t)(m0 + wm + mi * 16 + l4 * 4) * N + n0 + wn + ni * 16 + l15;
      #pragma unroll
      for (int r = 0; r < 4; ++r) dst[(size_t)r * N] = acc[mi][ni][r];
    }
}

// ---------------- RMSNorm + RoPE for Q and K (wave per row-head) ----------------
__global__ __launch_bounds__(256) void qk_rope_kernel(
    const float* __restrict__ QKV, const float* __restrict__ cosb,
    const float* __restrict__ sinb, const float* __restrict__ qs,
    const float* __restrict__ ks, uint16_t* __restrict__ Qb,
    uint16_t* __restrict__ Kb) {
  const int task = blockIdx.x * 4 + (threadIdx.x >> 6);
  const int lane = threadIdx.x & 63;
  const int hh = task % 24;        // 0..15 Q heads, 16..23 K heads
  const int row = task / 24;       // b*S + s
  const int s = row & (S_LEN - 1);
  const int b = row >> 11;
  const float c1 = cosb[s * 128 + lane], c2 = cosb[s * 128 + 64 + lane];
  const float s1 = sinb[s * 128 + lane], s2 = sinb[s * 128 + 64 + lane];
  const float* src = QKV + (size_t)row * 4096;
  float v1, v2, sc1, sc2, outscale;
  uint16_t* dst;
  if (hh < 16) {
    v1 = src[hh * 128 + lane]; v2 = src[hh * 128 + 64 + lane];
    sc1 = qs[lane]; sc2 = qs[lane + 64];
    outscale = 0.088388347648318447f;  // 1/sqrt(HD), folded softmax scale
    dst = Qb + ((size_t)(b * NH + hh) * S_LEN + s) * 128;
  } else {
    int g = hh - 16;
    v1 = src[2048 + g * 128 + lane]; v2 = src[2048 + g * 128 + 64 + lane];
    sc1 = ks[lane]; sc2 = ks[lane + 64];
    outscale = 1.0f;
    dst = Kb + ((size_t)(b * NG + g) * S_LEN + s) * 128;
  }
  float ss = v1 * v1 + v2 * v2;
  #pragma unroll
  for (int o = 1; o < 64; o <<= 1) ss += __shfl_xor(ss, o);
  float inv = rsqrtf(ss * (1.0f / 128.0f) + 1e-6f);
  float n1 = v1 * inv * sc1, n2 = v2 * inv * sc2;
  dst[lane] = f2bf((n1 * c1 - n2 * s1) * outscale);
  dst[lane + 64] = f2bf((n2 * c2 + n1 * s2) * outscale);
}

// ---------------- V f32 -> V_T[bg][128][S] bf16 ----------------
__global__ __launch_bounds__(256) void v_trans_kernel(
    const float* __restrict__ QKV, uint16_t* __restrict__ Vt) {
  __shared__ uint16_t T[128][72];
  const int s0 = blockIdx.x * 64;
  const int bg = blockIdx.y;
  const int b = bg >> 3, g = bg & 7;
  const int tid = threadIdx.x;
  const int tc = tid & 127, tr = tid >> 7;
  const float* src = QKV + ((size_t)(b * S_LEN + s0)) * 4096 + 3072 + g * 128;
  #pragma unroll
  for (int i = 0; i < 32; ++i) {
    int r = i * 2 + tr;
    T[tc][r] = f2bf(src[(size_t)r * 4096 + tc]);
  }
  __syncthreads();
  uint16_t* dst = Vt + (size_t)bg * 128 * S_LEN + s0;
  #pragma unroll
  for (int i = 0; i < 32; ++i) {
    int idx = i * 256 + tid;
    int d = idx >> 6, sof = idx & 63;
    dst[(size_t)d * S_LEN + sof] = T[d][sof];
  }
}

// ---------------- flash attention: 4 waves x 16 q-rows, KVBLK=64 ----------------
__global__ __launch_bounds__(256) void attn_kernel(
    const uint16_t* __restrict__ Qb, const uint16_t* __restrict__ Kb,
    const uint16_t* __restrict__ Vt, uint16_t* __restrict__ Ctx) {
  __shared__ uint8_t smem[32768 + 4 * 2304];
  uint16_t* Ks = (uint16_t*)smem;             // [64][128] xor-swizzled
  uint16_t* Vs = (uint16_t*)(smem + 16384);   // [128][64] xor-swizzled
  const int tid = threadIdx.x, lane = tid & 63, wid = tid >> 6;
  uint16_t* Ps = (uint16_t*)(smem + 32768) + wid * 1152;  // [16][72] per wave
  const int l15 = lane & 15, l4 = lane >> 4;

  const int q0 = blockIdx.x * 64;
  const int bh = blockIdx.y;
  const int b = bh >> 4, h = bh & 15;
  const int bg = b * NG + (h >> 1);  // GS = 2

  const uint16_t* Qh = Qb + (size_t)bh * S_LEN * HDIM;
  const uint16_t* Kh = Kb + (size_t)bg * S_LEN * HDIM;
  const uint16_t* Vh = Vt + (size_t)bg * HDIM * S_LEN;

  const int qrow = q0 + wid * 16 + l15;
  bf16x8 qf[4];
  #pragma unroll
  for (int kk = 0; kk < 4; ++kk)
    qf[kk] = *(const bf16x8*)(Qh + (size_t)qrow * HDIM + kk * 32 + l4 * 8);

  f32x4 acc[8];
  #pragma unroll
  for (int i = 0; i < 8; ++i) acc[i] = (f32x4){0.f, 0.f, 0.f, 0.f};
  float mrun = -1e30f, lrun = 0.f;

  const int nt = q0 / 64 + 1;
  const int k_row = lane >> 4, k_c = lane & 15;  // K chunk: 4 rows x 256B
  const int v_row = lane >> 3, v_c = lane & 7;   // V chunk: 8 rows x 128B

  for (int kt = 0; kt < nt; ++kt) {
    const int kv0 = kt * 64;
    #pragma unroll
    for (int i = 0; i < 4; ++i) {
      int chunk = wid * 4 + i;
      int row = chunk * 4 + k_row;
      int sc_ = (k_c ^ (row & 7)) * 8;  // pre-swizzled source (rule #21)
      gload16(Kh + (size_t)(kv0 + row) * HDIM + sc_, Ks + chunk * 512);
    }
    #pragma unroll
    for (int i = 0; i < 4; ++i) {
      int chunk = wid * 4 + i;
      int row = chunk * 8 + v_row;
      int sc_ = (v_c ^ (row & 7)) * 8;
      gload16(Vh + (size_t)row * S_LEN + kv0 + sc_, Vs + chunk * 512);
    }
    __syncthreads();

    // S^T[key][qrow] = K @ Q^T  (lane owns q-row = l15)
    f32x4 sc[4];
    #pragma unroll
    for (int i = 0; i < 4; ++i) sc[i] = (f32x4){0.f, 0.f, 0.f, 0.f};
    #pragma unroll
    for (int kk = 0; kk < 4; ++kk) {
      #pragma unroll
      for (int kc = 0; kc < 4; ++kc) {
        int key = kc * 16 + l15;
        int cc = (kk * 4 + l4) ^ (key & 7);
        bf16x8 kf = *(const bf16x8*)(Ks + key * 128 + cc * 8);
        sc[kc] = MFMA16(kf, qf[kk], sc[kc]);
      }
    }
    if (kt == nt - 1) {  // diagonal tile: causal mask
      #pragma unroll
      for (int kc = 0; kc < 4; ++kc)
        #pragma unroll
        for (int r = 0; r < 4; ++r)
          if (kv0 + kc * 16 + l4 * 4 + r > qrow) sc[kc][r] = -1e30f;
    }
    float tmax = -1e30f;
    #pragma unroll
    for (int kc = 0; kc < 4; ++kc)
      #pragma unroll
      for (int r = 0; r < 4; ++r) tmax = fmaxf(tmax, sc[kc][r]);
    tmax = fmaxf(tmax, __shfl_xor(tmax, 16));
    tmax = fmaxf(tmax, __shfl_xor(tmax, 32));
    float mnew = fmaxf(mrun, tmax);
    float corr = __expf(mrun - mnew);
    float tsum = 0.f;
    #pragma unroll
    for (int kc = 0; kc < 4; ++kc) {
      float p0 = __expf(sc[kc][0] - mnew);
      float p1 = __expf(sc[kc][1] - mnew);
      float p2 = __expf(sc[kc][2] - mnew);
      float p3 = __expf(sc[kc][3] - mnew);
      tsum += (p0 + p1) + (p2 + p3);
      ushort4 pw;
      pw.x = f2bf(p0); pw.y = f2bf(p1); pw.z = f2bf(p2); pw.w = f2bf(p3);
      *(ushort4*)(Ps + l15 * 72 + kc * 16 + l4 * 4) = pw;
    }
    tsum += __shfl_xor(tsum, 16);
    tsum += __shfl_xor(tsum, 32);
    lrun = lrun * corr + tsum;
    mrun = mnew;
    #pragma unroll
    for (int d0 = 0; d0 < 8; ++d0) acc[d0] *= corr;

    // ctx^T[d][qrow] += V^T @ P^T
    #pragma unroll
    for (int half = 0; half < 2; ++half) {
      bf16x8 pf = *(const bf16x8*)(Ps + l15 * 72 + half * 32 + l4 * 8);
      #pragma unroll
      for (int d0 = 0; d0 < 8; ++d0) {
        int d = d0 * 16 + l15;
        int cc = (half * 4 + l4) ^ (d & 7);
        bf16x8 vf = *(const bf16x8*)(Vs + d * 64 + cc * 8);
        acc[d0] = MFMA16(vf, pf, acc[d0]);
      }
    }
    __syncthreads();
  }
  float inv = 1.0f / lrun;
  uint16_t* dst = Ctx + ((size_t)(b * S_LEN + qrow) * NH + h) * HDIM;
  #pragma unroll
  for (int d0 = 0; d0 < 8; ++d0) {
    ushort4 o;
    o.x = f2bf(acc[d0][0] * inv);
    o.y = f2bf(acc[d0][1] * inv);
    o.z = f2bf(acc[d0][2] * inv);
    o.w = f2bf(acc[d0][3] * inv);
    *(ushort4*)(dst + d0 * 16 + l4 * 4) = o;
  }
}

extern "C" void kernel_launch(void* const* d_in, const int* in_sizes, int n_in,
                              void* d_out, int out_size, void* d_ws, size_t ws_size,
                              hipStream_t stream) {
  const float* x    = (const float*)d_in[0];
  // d_in[1] = mask (unused; causal is known)
  const float* cosb = (const float*)d_in[2];
  const float* sinb = (const float*)d_in[3];
  const float* Wq   = (const float*)d_in[4];
  const float* Wk   = (const float*)d_in[5];
  const float* Wv   = (const float*)d_in[6];
  const float* Wo   = (const float*)d_in[7];
  const float* qs   = (const float*)d_in[8];
  const float* ks   = (const float*)d_in[9];

  char* ws = (char*)d_ws;
  uint16_t* Xb    = (uint16_t*)(ws);                         // 16 MB  [4096][2048]
  uint16_t* WallT = (uint16_t*)(ws + (16ull << 20));         // 16 MB  [4096][2048]
  uint16_t* WoT   = (uint16_t*)(ws + (32ull << 20));         //  8 MB  [2048][2048]
  float*    QKV   = (float*)   (ws + (40ull << 20));         // 64 MB  [4096][4096]
  uint16_t* Qb    = (uint16_t*)(ws + (104ull << 20));        // 16 MB  [B*H][S][128]
  uint16_t* Kb    = (uint16_t*)(ws + (120ull << 20));        //  8 MB  [B*G][S][128]
  uint16_t* Vt    = (uint16_t*)(ws + (128ull << 20));        //  8 MB  [B*G][128][S]
  uint16_t* Ctx   = (uint16_t*)(ws + (136ull << 20));        // 16 MB  [4096][2048]
  float* out = (float*)d_out;

  cvt_x_kernel<<<8192, 256, 0, stream>>>(x, Xb, 2097152);
  trans_cvt_kernel<<<dim3(64, 64), 256, 0, stream>>>(Wq, WallT, 2048, 2048);
  trans_cvt_kernel<<<dim3(32, 64), 256, 0, stream>>>(Wk, WallT + 2048 * 2048, 2048, 1024);
  trans_cvt_kernel<<<dim3(32, 64), 256, 0, stream>>>(Wv, WallT + 3072 * 2048, 2048, 1024);
  trans_cvt_kernel<<<dim3(64, 64), 256, 0, stream>>>(Wo, WoT, 2048, 2048);
  gemm_bt_kernel<<<dim3(32, 32), 256, 0, stream>>>(Xb, WallT, QKV, 4096, 4096, 2048);
  qk_rope_kernel<<<24576, 256, 0, stream>>>(QKV, cosb, sinb, qs, ks, Qb, Kb);
  v_trans_kernel<<<dim3(32, 16), 256, 0, stream>>>(QKV, Vt);
  attn_kernel<<<dim3(32, 32), 256, 0, stream>>>(Qb, Kb, Vt, Ctx);
  gemm_bt_kernel<<<dim3(16, 32), 256, 0, stream>>>(Ctx, WoT, out, 4096, 2048, 2048);
}

// Round 2
// 392.286 us; speedup vs baseline: 1.1580x; 1.1580x over previous
//
#include <hip/hip_runtime.h>
#include <stdint.h>

#define S_LEN 2048
#define NH 16
#define NG 8
#define HDIM 128

typedef __bf16 bf16x8 __attribute__((ext_vector_type(8)));
typedef float f32x4 __attribute__((ext_vector_type(4)));

#define MFMA16(a, b, c) __builtin_amdgcn_mfma_f32_16x16x32_bf16((a), (b), (c), 0, 0, 0)

__device__ __forceinline__ uint16_t f2bf(float f) {
  union { float f; uint32_t u; } v; v.f = f;
  return (uint16_t)((v.u + 0x7fffu + ((v.u >> 16) & 1u)) >> 16);
}

__device__ __forceinline__ void gload16(const void* g, void* l) {
  __builtin_amdgcn_global_load_lds(
      (__attribute__((address_space(1))) const void*)g,
      (__attribute__((address_space(3))) void*)l, 16, 0, 0);
}

// ---------------- x -> bf16 ----------------
__global__ __launch_bounds__(256) void cvt_x_kernel(
    const float* __restrict__ x, uint16_t* __restrict__ xb, int n4) {
  int i = blockIdx.x * 256 + threadIdx.x;
  if (i >= n4) return;
  float4 v = ((const float4*)x)[i];
  ushort4 o;
  o.x = f2bf(v.x); o.y = f2bf(v.y); o.z = f2bf(v.z); o.w = f2bf(v.w);
  ((ushort4*)xb)[i] = o;
}

// ---------------- W[k][n] f32 -> dst[n][k] bf16 ----------------
__global__ __launch_bounds__(256) void trans_cvt_kernel(
    const float* __restrict__ src, uint16_t* __restrict__ dst, int K, int N) {
  __shared__ float T[32][33];
  int n0 = blockIdx.x * 32, k0 = blockIdx.y * 32;
  int tx = threadIdx.x & 31, ty = threadIdx.x >> 5;  // 32 x 8
  #pragma unroll
  for (int i = 0; i < 4; ++i)
    T[ty + i * 8][tx] = src[(size_t)(k0 + ty + i * 8) * N + n0 + tx];
  __syncthreads();
  #pragma unroll
  for (int i = 0; i < 4; ++i)
    dst[(size_t)(n0 + ty + i * 8) * K + k0 + tx] = f2bf(T[tx][ty + i * 8]);
}

// ---------------- C[M][N] f32 = A[M][K]bf16 @ BT[N][K]bf16 (m97 structure) ----------------
__global__ __launch_bounds__(256) void gemm_bt_kernel(
    const uint16_t* __restrict__ A, const uint16_t* __restrict__ BT,
    float* __restrict__ C, int M, int N, int K) {
  __shared__ uint8_t smem[32768];
  uint16_t* As = (uint16_t*)smem;            // [128][64]
  uint16_t* Bs = (uint16_t*)(smem + 16384);  // [128][64]
  const int tid = threadIdx.x, lane = tid & 63, wid = tid >> 6;
  const int l15 = lane & 15, l4 = lane >> 4;
  const int m0 = blockIdx.y * 128, n0 = blockIdx.x * 128;
  const int wm = (wid >> 1) * 64, wn = (wid & 1) * 64;
  const int s_row = lane >> 3, s_col = (lane & 7) * 8;  // 1KB chunk = 8 rows x 128B

  f32x4 acc[4][4];
  #pragma unroll
  for (int i = 0; i < 4; ++i)
    #pragma unroll
    for (int j = 0; j < 4; ++j) acc[i][j] = (f32x4){0.f, 0.f, 0.f, 0.f};

  for (int k0 = 0; k0 < K; k0 += 64) {
    #pragma unroll
    for (int i = 0; i < 4; ++i) {
      int chunk = wid * 4 + i;
      int row = chunk * 8 + s_row;
      gload16(A + (size_t)(m0 + row) * K + k0 + s_col, As + chunk * 512);
    }
    #pragma unroll
    for (int i = 0; i < 4; ++i) {
      int chunk = wid * 4 + i;
      int row = chunk * 8 + s_row;
      gload16(BT + (size_t)(n0 + row) * K + k0 + s_col, Bs + chunk * 512);
    }
    __syncthreads();
    #pragma unroll
    for (int kk = 0; kk < 2; ++kk) {
      bf16x8 af[4], bfr[4];
      #pragma unroll
      for (int mi = 0; mi < 4; ++mi)
        af[mi] = *(const bf16x8*)(As + (wm + mi * 16 + l15) * 64 + kk * 32 + l4 * 8);
      #pragma unroll
      for (int ni = 0; ni < 4; ++ni)
        bfr[ni] = *(const bf16x8*)(Bs + (wn + ni * 16 + l15) * 64 + kk * 32 + l4 * 8);
      #pragma unroll
      for (int mi = 0; mi < 4; ++mi)
        #pragma unroll
        for (int ni = 0; ni < 4; ++ni)
          acc[mi][ni] = MFMA16(af[mi], bfr[ni], acc[mi][ni]);
    }
    __syncthreads();
  }
  #pragma unroll
  for (int mi = 0; mi < 4; ++mi)
    #pragma unroll
    for (int ni = 0; ni < 4; ++ni) {
      float* dst = C + (size_t)(m0 + wm + mi * 16 + l4 * 4) * N + n0 + wn + ni * 16 + l15;
      #pragma unroll
      for (int r = 0; r < 4; ++r) dst[(size_t)r * N] = acc[mi][ni][r];
    }
}

// ---------------- RMSNorm + RoPE for Q and K (wave per row-head) ----------------
__global__ __launch_bounds__(256) void qk_rope_kernel(
    const float* __restrict__ QKV, const float* __restrict__ cosb,
    const float* __restrict__ sinb, const float* __restrict__ qs,
    const float* __restrict__ ks, uint16_t* __restrict__ Qb,
    uint16_t* __restrict__ Kb) {
  const int task = blockIdx.x * 4 + (threadIdx.x >> 6);
  const int lane = threadIdx.x & 63;
  const int hh = task % 24;        // 0..15 Q heads, 16..23 K heads
  const int row = task / 24;       // b*S + s
  const int s = row & (S_LEN - 1);
  const int b = row >> 11;
  const float c1 = cosb[s * 128 + lane], c2 = cosb[s * 128 + 64 + lane];
  const float s1 = sinb[s * 128 + lane], s2 = sinb[s * 128 + 64 + lane];
  const float* src = QKV + (size_t)row * 4096;
  float v1, v2, sc1, sc2, outscale;
  uint16_t* dst;
  if (hh < 16) {
    v1 = src[hh * 128 + lane]; v2 = src[hh * 128 + 64 + lane];
    sc1 = qs[lane]; sc2 = qs[lane + 64];
    outscale = 0.088388347648318447f;  // 1/sqrt(HD), folded softmax scale
    dst = Qb + ((size_t)(b * NH + hh) * S_LEN + s) * 128;
  } else {
    int g = hh - 16;
    v1 = src[2048 + g * 128 + lane]; v2 = src[2048 + g * 128 + 64 + lane];
    sc1 = ks[lane]; sc2 = ks[lane + 64];
    outscale = 1.0f;
    dst = Kb + ((size_t)(b * NG + g) * S_LEN + s) * 128;
  }
  float ss = v1 * v1 + v2 * v2;
  #pragma unroll
  for (int o = 1; o < 64; o <<= 1) ss += __shfl_xor(ss, o);
  float inv = rsqrtf(ss * (1.0f / 128.0f) + 1e-6f);
  float n1 = v1 * inv * sc1, n2 = v2 * inv * sc2;
  dst[lane] = f2bf((n1 * c1 - n2 * s1) * outscale);
  dst[lane + 64] = f2bf((n2 * c2 + n1 * s2) * outscale);
}

// ---------------- V f32 -> V_T[bg][128][S] bf16 ----------------
__global__ __launch_bounds__(256) void v_trans_kernel(
    const float* __restrict__ QKV, uint16_t* __restrict__ Vt) {
  __shared__ uint16_t T[128][72];
  const int s0 = blockIdx.x * 64;
  const int bg = blockIdx.y;
  const int b = bg >> 3, g = bg & 7;
  const int tid = threadIdx.x;
  const int tc = tid & 127, tr = tid >> 7;
  const float* src = QKV + ((size_t)(b * S_LEN + s0)) * 4096 + 3072 + g * 128;
  #pragma unroll
  for (int i = 0; i < 32; ++i) {
    int r = i * 2 + tr;
    T[tc][r] = f2bf(src[(size_t)r * 4096 + tc]);
  }
  __syncthreads();
  uint16_t* dst = Vt + (size_t)bg * 128 * S_LEN + s0;
  #pragma unroll
  for (int i = 0; i < 32; ++i) {
    int idx = i * 256 + tid;
    int d = idx >> 6, sof = idx & 63;
    dst[(size_t)d * S_LEN + sof] = T[d][sof];
  }
}

// ---------------- flash attention ----------------
// 4 waves x 16 q-rows = 64-row q-tile. Block x handles q-tiles {x, 31-x}
// (constant 33 KV-steps -> no causal load imbalance). K/V double-buffered in
// LDS, staged with global_load_lds; ONE raw barrier per KV step with a full
// vmcnt drain AFTER compute (T3-minimum 2-phase: next tile's loads fly under
// the current tile's MFMA+softmax).
__global__ __launch_bounds__(256) void attn_kernel(
    const uint16_t* __restrict__ Qb, const uint16_t* __restrict__ Kb,
    const uint16_t* __restrict__ Vt, uint16_t* __restrict__ Ctx) {
  __shared__ uint8_t smem[65536 + 4 * 2304];
  // Ks[buf]: smem + buf*16384            [64][128] xor-swizzled
  // Vs[buf]: smem + 32768 + buf*16384    [128][64] xor-swizzled
  const int tid = threadIdx.x, lane = tid & 63, wid = tid >> 6;
  uint16_t* Ps = (uint16_t*)(smem + 65536) + wid * 1152;  // [16][72] per wave
  const int l15 = lane & 15, l4 = lane >> 4;

  const int bh = blockIdx.y;
  const int b = bh >> 4, h = bh & 15;
  const int bg = b * NG + (h >> 1);  // GS = 2

  const uint16_t* Qh = Qb + (size_t)bh * S_LEN * HDIM;
  const uint16_t* Kh = Kb + (size_t)bg * S_LEN * HDIM;
  const uint16_t* Vh = Vt + (size_t)bg * HDIM * S_LEN;

  const int k_row = lane >> 4, k_c = lane & 15;  // K chunk: 4 rows x 256B
  const int v_row = lane >> 3, v_c = lane & 7;   // V chunk: 8 rows x 128B

#define STAGE(kt_, buf_)                                                      \
  do {                                                                        \
    const int kv0_ = (kt_) * 64;                                              \
    uint16_t* KsB_ = (uint16_t*)(smem + (buf_) * 16384);                      \
    uint16_t* VsB_ = (uint16_t*)(smem + 32768 + (buf_) * 16384);              \
    _Pragma("unroll")                                                         \
    for (int i_ = 0; i_ < 4; ++i_) {                                          \
      int chunk_ = wid * 4 + i_;                                              \
      int row_ = chunk_ * 4 + k_row;                                          \
      int sc_ = (k_c ^ (row_ & 7)) * 8;                                       \
      gload16(Kh + (size_t)(kv0_ + row_) * HDIM + sc_, KsB_ + chunk_ * 512);  \
    }                                                                         \
    _Pragma("unroll")                                                         \
    for (int i_ = 0; i_ < 4; ++i_) {                                          \
      int chunk_ = wid * 4 + i_;                                              \
      int row_ = chunk_ * 8 + v_row;                                          \
      int sc_ = (v_c ^ (row_ & 7)) * 8;                                       \
      gload16(Vh + (size_t)row_ * S_LEN + kv0_ + sc_, VsB_ + chunk_ * 512);   \
    }                                                                         \
  } while (0)

  for (int half = 0; half < 2; ++half) {
    const int qtile = half ? (31 - (int)blockIdx.x) : (int)blockIdx.x;
    const int q0 = qtile * 64;
    const int qrow = q0 + wid * 16 + l15;

    bf16x8 qf[4];
    #pragma unroll
    for (int kk = 0; kk < 4; ++kk)
      qf[kk] = *(const bf16x8*)(Qh + (size_t)qrow * HDIM + kk * 32 + l4 * 8);

    f32x4 acc[8];
    #pragma unroll
    for (int i = 0; i < 8; ++i) acc[i] = (f32x4){0.f, 0.f, 0.f, 0.f};
    float mrun = -1e30f, lrun = 0.f;

    const int nt = qtile + 1;
    int cur = 0;
    STAGE(0, 0);
    asm volatile("s_waitcnt vmcnt(0)\ns_barrier" ::: "memory");

    for (int kt = 0; kt < nt; ++kt) {
      const int kv0 = kt * 64;
      if (kt + 1 < nt) STAGE(kt + 1, cur ^ 1);

      uint16_t* Ks = (uint16_t*)(smem + cur * 16384);
      uint16_t* Vs = (uint16_t*)(smem + 32768 + cur * 16384);

      // S^T[key][qrow] = K @ Q^T  (lane owns q-row = l15)
      f32x4 sc[4];
      #pragma unroll
      for (int i = 0; i < 4; ++i) sc[i] = (f32x4){0.f, 0.f, 0.f, 0.f};
      __builtin_amdgcn_s_setprio(1);
      #pragma unroll
      for (int kk = 0; kk < 4; ++kk) {
        #pragma unroll
        for (int kc = 0; kc < 4; ++kc) {
          int key = kc * 16 + l15;
          int cc = (kk * 4 + l4) ^ (key & 7);
          bf16x8 kf = *(const bf16x8*)(Ks + key * 128 + cc * 8);
          sc[kc] = MFMA16(kf, qf[kk], sc[kc]);
        }
      }
      __builtin_amdgcn_s_setprio(0);
      if (kt == nt - 1) {  // diagonal tile: causal mask
        #pragma unroll
        for (int kc = 0; kc < 4; ++kc)
          #pragma unroll
          for (int r = 0; r < 4; ++r)
            if (kv0 + kc * 16 + l4 * 4 + r > qrow) sc[kc][r] = -1e30f;
      }
      float tmax = -1e30f;
      #pragma unroll
      for (int kc = 0; kc < 4; ++kc)
        #pragma unroll
        for (int r = 0; r < 4; ++r) tmax = fmaxf(tmax, sc[kc][r]);
      tmax = fmaxf(tmax, __shfl_xor(tmax, 16));
      tmax = fmaxf(tmax, __shfl_xor(tmax, 32));
      float mnew = fmaxf(mrun, tmax);
      float corr = __expf(mrun - mnew);
      float tsum = 0.f;
      #pragma unroll
      for (int kc = 0; kc < 4; ++kc) {
        float p0 = __expf(sc[kc][0] - mnew);
        float p1 = __expf(sc[kc][1] - mnew);
        float p2 = __expf(sc[kc][2] - mnew);
        float p3 = __expf(sc[kc][3] - mnew);
        tsum += (p0 + p1) + (p2 + p3);
        ushort4 pw;
        pw.x = f2bf(p0); pw.y = f2bf(p1); pw.z = f2bf(p2); pw.w = f2bf(p3);
        *(ushort4*)(Ps + l15 * 72 + kc * 16 + l4 * 4) = pw;
      }
      tsum += __shfl_xor(tsum, 16);
      tsum += __shfl_xor(tsum, 32);
      lrun = lrun * corr + tsum;
      mrun = mnew;
      #pragma unroll
      for (int d0 = 0; d0 < 8; ++d0) acc[d0] *= corr;

      // ctx^T[d][qrow] += V^T @ P^T
      __builtin_amdgcn_s_setprio(1);
      #pragma unroll
      for (int hf = 0; hf < 2; ++hf) {
        bf16x8 pf = *(const bf16x8*)(Ps + l15 * 72 + hf * 32 + l4 * 8);
        #pragma unroll
        for (int d0 = 0; d0 < 8; ++d0) {
          int d = d0 * 16 + l15;
          int cc = (hf * 4 + l4) ^ (d & 7);
          bf16x8 vf = *(const bf16x8*)(Vs + d * 64 + cc * 8);
          acc[d0] = MFMA16(vf, pf, acc[d0]);
        }
      }
      __builtin_amdgcn_s_setprio(0);

      // drain next tile's loads, then one barrier: buf[cur] may be
      // overwritten next iteration, buf[cur^1] is now fully staged.
      asm volatile("s_waitcnt vmcnt(0)\ns_barrier" ::: "memory");
      cur ^= 1;
    }

    float inv = 1.0f / lrun;
    uint16_t* dst = Ctx + ((size_t)(b * S_LEN + qrow) * NH + h) * HDIM;
    #pragma unroll
    for (int d0 = 0; d0 < 8; ++d0) {
      ushort4 o;
      o.x = f2bf(acc[d0][0] * inv);
      o.y = f2bf(acc[d0][1] * inv);
      o.z = f2bf(acc[d0][2] * inv);
      o.w = f2bf(acc[d0][3] * inv);
      *(ushort4*)(dst + d0 * 16 + l4 * 4) = o;
    }
  }
#undef STAGE
}

extern "C" void kernel_launch(void* const* d_in, const int* in_sizes, int n_in,
                              void* d_out, int out_size, void* d_ws, size_t ws_size,
                              hipStream_t stream) {
  const float* x    = (const float*)d_in[0];
  // d_in[1] = mask (unused; causal is known)
  const float* cosb = (const float*)d_in[2];
  const float* sinb = (const float*)d_in[3];
  const float* Wq   = (const float*)d_in[4];
  const float* Wk   = (const float*)d_in[5];
  const float* Wv   = (const float*)d_in[6];
  const float* Wo   = (const float*)d_in[7];
  const float* qs   = (const float*)d_in[8];
  const float* ks   = (const float*)d_in[9];

  char* ws = (char*)d_ws;
  uint16_t* Xb    = (uint16_t*)(ws);                         // 16 MB  [4096][2048]
  uint16_t* WallT = (uint16_t*)(ws + (16ull << 20));         // 16 MB  [4096][2048]
  uint16_t* WoT   = (uint16_t*)(ws + (32ull << 20));         //  8 MB  [2048][2048]
  float*    QKV   = (float*)   (ws + (40ull << 20));         // 64 MB  [4096][4096]
  uint16_t* Qb    = (uint16_t*)(ws + (104ull << 20));        // 16 MB  [B*H][S][128]
  uint16_t* Kb    = (uint16_t*)(ws + (120ull << 20));        //  8 MB  [B*G][S][128]
  uint16_t* Vt    = (uint16_t*)(ws + (128ull << 20));        //  8 MB  [B*G][128][S]
  uint16_t* Ctx   = (uint16_t*)(ws + (136ull << 20));        // 16 MB  [4096][2048]
  float* out = (float*)d_out;

  cvt_x_kernel<<<8192, 256, 0, stream>>>(x, Xb, 2097152);
  trans_cvt_kernel<<<dim3(64, 64), 256, 0, stream>>>(Wq, WallT, 2048, 2048);
  trans_cvt_kernel<<<dim3(32, 64), 256, 0, stream>>>(Wk, WallT + 2048 * 2048, 2048, 1024);
  trans_cvt_kernel<<<dim3(32, 64), 256, 0, stream>>>(Wv, WallT + 3072 * 2048, 2048, 1024);
  trans_cvt_kernel<<<dim3(64, 64), 256, 0, stream>>>(Wo, WoT, 2048, 2048);
  gemm_bt_kernel<<<dim3(32, 32), 256, 0, stream>>>(Xb, WallT, QKV, 4096, 4096, 2048);
  qk_rope_kernel<<<24576, 256, 0, stream>>>(QKV, cosb, sinb, qs, ks, Qb, Kb);
  v_trans_kernel<<<dim3(32, 16), 256, 0, stream>>>(QKV, Vt);
  attn_kernel<<<dim3(16, 32), 256, 0, stream>>>(Qb, Kb, Vt, Ctx);
  gemm_bt_kernel<<<dim3(16, 32), 256, 0, stream>>>(Ctx, WoT, out, 4096, 2048, 2048);
}

// Round 3
// 358.274 us; speedup vs baseline: 1.2679x; 1.0949x over previous
//
#include <hip/hip_runtime.h>
#include <stdint.h>

#define S_LEN 2048
#define NH 16
#define NG 8
#define HDIM 128

typedef __bf16 bf16x8 __attribute__((ext_vector_type(8)));
typedef float f32x4 __attribute__((ext_vector_type(4)));

#define MFMA16(a, b, c) __builtin_amdgcn_mfma_f32_16x16x32_bf16((a), (b), (c), 0, 0, 0)

__device__ __forceinline__ uint16_t f2bf(float f) {
  union { float f; uint32_t u; } v; v.f = f;
  return (uint16_t)((v.u + 0x7fffu + ((v.u >> 16) & 1u)) >> 16);
}

__device__ __forceinline__ void gload16(const void* g, void* l) {
  __builtin_amdgcn_global_load_lds(
      (__attribute__((address_space(1))) const void*)g,
      (__attribute__((address_space(3))) void*)l, 16, 0, 0);
}

// ---------------- x -> bf16 ----------------
__global__ __launch_bounds__(256) void cvt_x_kernel(
    const float* __restrict__ x, uint16_t* __restrict__ xb, int n4) {
  int i = blockIdx.x * 256 + threadIdx.x;
  if (i >= n4) return;
  float4 v = ((const float4*)x)[i];
  ushort4 o;
  o.x = f2bf(v.x); o.y = f2bf(v.y); o.z = f2bf(v.z); o.w = f2bf(v.w);
  ((ushort4*)xb)[i] = o;
}

// ---------------- W[k][n] f32 -> dst[n][k] bf16 ----------------
__global__ __launch_bounds__(256) void trans_cvt_kernel(
    const float* __restrict__ src, uint16_t* __restrict__ dst, int K, int N) {
  __shared__ float T[32][33];
  int n0 = blockIdx.x * 32, k0 = blockIdx.y * 32;
  int tx = threadIdx.x & 31, ty = threadIdx.x >> 5;  // 32 x 8
  #pragma unroll
  for (int i = 0; i < 4; ++i)
    T[ty + i * 8][tx] = src[(size_t)(k0 + ty + i * 8) * N + n0 + tx];
  __syncthreads();
  #pragma unroll
  for (int i = 0; i < 4; ++i)
    dst[(size_t)(n0 + ty + i * 8) * K + k0 + tx] = f2bf(T[tx][ty + i * 8]);
}

// ================= 8-phase pipelined GEMM (T2+T3+T4+T5, derived waits) ======
// C[M][N] f32 = A[M][K]bf16 @ BT[N][K]bf16. Tile BM x 256, BK=64, 8 waves
// (2M x 4N), 512 threads. K-tile split into K-halves (A_k0,A_k1,B_k0,B_k1,
// 32-k each). 4 phases/tile: (k0,n0),(k0,n1),(k1,n1),(k1,n0); A-frags
// register-reused across the nh pair. Issues: ph0:A_k1(u+1) ph1:B_k1(u+1)
// ph2:A_k0(u+2) ph3:B_k0(u+2); one boundary vmcnt(LA+2) per tile (never 0
// mid-loop). LDS pair-interleave XOR swizzle (2-way conflict = free),
// pre-swizzled global source (same involution).
//
// Swizzled half layout (rows of 32 bf16 = 64B): byte = pair*128 + slot'*16,
// pair=row>>1, slot=(row&1)*4+c2, slot' = slot ^ (pair&7).
template <int NISSUE>
__device__ __forceinline__ void stage_half(const uint16_t* __restrict__ g,
                                           int ldg, char* lds, int tid) {
  #pragma unroll
  for (int i = 0; i < NISSUE; ++i) {
    int ch = i * 512 + tid;
    int pair = ch >> 3, slotd = ch & 7;
    int slotl = slotd ^ (pair & 7);
    int row = pair * 2 + (slotl >> 2), c2 = slotl & 3;
    gload16(g + (size_t)row * ldg + c2 * 8, lds + ch * 16);
  }
}

__device__ __forceinline__ bf16x8 ldsfrag(const char* half_base, int row, int l4) {
  int pair = row >> 1;
  int slot = ((row & 1) << 2) | l4;
  return *(const bf16x8*)(half_base + pair * 128 + ((slot ^ (pair & 7)) * 16));
}

#define BAR() asm volatile("s_barrier" ::: "memory")

template <int BM>
__global__ __launch_bounds__(512, 2) void gemm8p_kernel(
    const uint16_t* __restrict__ A, const uint16_t* __restrict__ BT,
    float* __restrict__ C, int M, int N, int K, int gridN) {
  extern __shared__ char smem[];
  constexpr int MI = BM / 32;       // m-frags per wave
  constexpr int LA = BM / 128;      // gloads/thread per A-half
  constexpr int ABYTES = BM * 64;   // bytes per A-half
  const int tid = threadIdx.x, lane = tid & 63;
  const int wid = tid >> 6;
  const int l15 = lane & 15, l4 = lane >> 4;
  const int wm = wid >> 2, wn = wid & 3;

  // XCD-aware swizzle (grid is a multiple of 8)
  const int nwg = gridDim.x, bid = blockIdx.x;
  const int cpx = nwg >> 3;
  const int swz = (bid & 7) * cpx + (bid >> 3);
  const int m0 = (swz / gridN) * BM, n0 = (swz % gridN) * 256;

  const uint16_t* Ag = A + (size_t)m0 * K;
  const uint16_t* Bg = BT + (size_t)n0 * K;
  const int NT = K >> 6;

#define ABASE(p, k) (smem + (((p) << 1) | (k)) * ABYTES)
#define BBASE(p, k) (smem + 4 * ABYTES + (((p) << 1) | (k)) * 16384)

  f32x4 acc[MI][4];
  #pragma unroll
  for (int mi = 0; mi < MI; ++mi)
    #pragma unroll
    for (int ni = 0; ni < 4; ++ni) acc[mi][ni] = (f32x4){0.f, 0.f, 0.f, 0.f};

  // prologue: A_k0(0) B_k0(0) A_k1(0) B_k1(0) A_k0(1) B_k0(1)
  stage_half<LA>(Ag, K, ABASE(0, 0), tid);
  stage_half<2>(Bg, K, BBASE(0, 0), tid);
  stage_half<LA>(Ag + 32, K, ABASE(0, 1), tid);
  stage_half<2>(Bg + 32, K, BBASE(0, 1), tid);
  stage_half<LA>(Ag + 64, K, ABASE(1, 0), tid);
  stage_half<2>(Bg + 64, K, BBASE(1, 0), tid);
  if constexpr (BM == 256) asm volatile("s_waitcnt vmcnt(4)" ::: "memory");
  else                     asm volatile("s_waitcnt vmcnt(3)" ::: "memory");
  BAR();

  int par = 0;
  const int arow = wm * (BM / 2) + l15;
  for (int u = 0; u < NT; ++u, par ^= 1) {
    const int k0 = u * 64;
    bf16x8 af[MI], bf0, bf1;
    // ---- phase 0: (kh=0, nh=0) ----
    #pragma unroll
    for (int mi = 0; mi < MI; ++mi) af[mi] = ldsfrag(ABASE(par, 0), arow + mi * 16, l4);
    bf0 = ldsfrag(BBASE(par, 0), wn * 64 + l15, l4);
    bf1 = ldsfrag(BBASE(par, 0), wn * 64 + 16 + l15, l4);
    if (u + 1 < NT) stage_half<LA>(Ag + (k0 + 96), K, ABASE(par ^ 1, 1), tid);
    BAR();
    __builtin_amdgcn_s_setprio(1);
    #pragma unroll
    for (int mi = 0; mi < MI; ++mi) {
      acc[mi][0] = MFMA16(af[mi], bf0, acc[mi][0]);
      acc[mi][1] = MFMA16(af[mi], bf1, acc[mi][1]);
    }
    __builtin_amdgcn_s_setprio(0);
    BAR();
    // ---- phase 1: (kh=0, nh=1) — af reused ----
    bf0 = ldsfrag(BBASE(par, 0), wn * 64 + 32 + l15, l4);
    bf1 = ldsfrag(BBASE(par, 0), wn * 64 + 48 + l15, l4);
    if (u + 1 < NT) stage_half<2>(Bg + (k0 + 96), K, BBASE(par ^ 1, 1), tid);
    BAR();
    __builtin_amdgcn_s_setprio(1);
    #pragma unroll
    for (int mi = 0; mi < MI; ++mi) {
      acc[mi][2] = MFMA16(af[mi], bf0, acc[mi][2]);
      acc[mi][3] = MFMA16(af[mi], bf1, acc[mi][3]);
    }
    __builtin_amdgcn_s_setprio(0);
    BAR();
    // ---- phase 2: (kh=1, nh=1) ----
    #pragma unroll
    for (int mi = 0; mi < MI; ++mi) af[mi] = ldsfrag(ABASE(par, 1), arow + mi * 16, l4);
    bf0 = ldsfrag(BBASE(par, 1), wn * 64 + 32 + l15, l4);
    bf1 = ldsfrag(BBASE(par, 1), wn * 64 + 48 + l15, l4);
    if (u + 2 < NT) stage_half<LA>(Ag + (k0 + 128), K, ABASE(par, 0), tid);
    BAR();
    __builtin_amdgcn_s_setprio(1);
    #pragma unroll
    for (int mi = 0; mi < MI; ++mi) {
      acc[mi][2] = MFMA16(af[mi], bf0, acc[mi][2]);
      acc[mi][3] = MFMA16(af[mi], bf1, acc[mi][3]);
    }
    __builtin_amdgcn_s_setprio(0);
    BAR();
    // ---- phase 3: (kh=1, nh=0) — af reused ----
    bf0 = ldsfrag(BBASE(par, 1), wn * 64 + l15, l4);
    bf1 = ldsfrag(BBASE(par, 1), wn * 64 + 16 + l15, l4);
    if (u + 2 < NT) stage_half<2>(Bg + (k0 + 128), K, BBASE(par, 0), tid);
    BAR();
    __builtin_amdgcn_s_setprio(1);
    #pragma unroll
    for (int mi = 0; mi < MI; ++mi) {
      acc[mi][0] = MFMA16(af[mi], bf0, acc[mi][0]);
      acc[mi][1] = MFMA16(af[mi], bf1, acc[mi][1]);
    }
    __builtin_amdgcn_s_setprio(0);
    // boundary: land all of tile u+1; only tile u+2's two halves may fly
    if (u + 2 < NT) {
      if constexpr (BM == 256) asm volatile("s_waitcnt vmcnt(4)" ::: "memory");
      else                     asm volatile("s_waitcnt vmcnt(3)" ::: "memory");
    } else {
      asm volatile("s_waitcnt vmcnt(0)" ::: "memory");
    }
    BAR();
  }

  #pragma unroll
  for (int mi = 0; mi < MI; ++mi)
    #pragma unroll
    for (int ni = 0; ni < 4; ++ni) {
      float* dst = C + (size_t)(m0 + wm * (BM / 2) + mi * 16 + l4 * 4) * N +
                   n0 + wn * 64 + ni * 16 + l15;
      #pragma unroll
      for (int r = 0; r < 4; ++r) dst[(size_t)r * N] = acc[mi][ni][r];
    }
#undef ABASE
#undef BBASE
}

// ---------------- RMSNorm + RoPE for Q and K (wave per row-head) ----------------
__global__ __launch_bounds__(256) void qk_rope_kernel(
    const float* __restrict__ QKV, const float* __restrict__ cosb,
    const float* __restrict__ sinb, const float* __restrict__ qs,
    const float* __restrict__ ks, uint16_t* __restrict__ Qb,
    uint16_t* __restrict__ Kb) {
  const int task = blockIdx.x * 4 + (threadIdx.x >> 6);
  const int lane = threadIdx.x & 63;
  const int hh = task % 24;        // 0..15 Q heads, 16..23 K heads
  const int row = task / 24;       // b*S + s
  const int s = row & (S_LEN - 1);
  const int b = row >> 11;
  const float c1 = cosb[s * 128 + lane], c2 = cosb[s * 128 + 64 + lane];
  const float s1 = sinb[s * 128 + lane], s2 = sinb[s * 128 + 64 + lane];
  const float* src = QKV + (size_t)row * 4096;
  float v1, v2, sc1, sc2, outscale;
  uint16_t* dst;
  if (hh < 16) {
    v1 = src[hh * 128 + lane]; v2 = src[hh * 128 + 64 + lane];
    sc1 = qs[lane]; sc2 = qs[lane + 64];
    outscale = 0.088388347648318447f;  // 1/sqrt(HD), folded softmax scale
    dst = Qb + ((size_t)(b * NH + hh) * S_LEN + s) * 128;
  } else {
    int g = hh - 16;
    v1 = src[2048 + g * 128 + lane]; v2 = src[2048 + g * 128 + 64 + lane];
    sc1 = ks[lane]; sc2 = ks[lane + 64];
    outscale = 1.0f;
    dst = Kb + ((size_t)(b * NG + g) * S_LEN + s) * 128;
  }
  float ss = v1 * v1 + v2 * v2;
  #pragma unroll
  for (int o = 1; o < 64; o <<= 1) ss += __shfl_xor(ss, o);
  float inv = rsqrtf(ss * (1.0f / 128.0f) + 1e-6f);
  float n1 = v1 * inv * sc1, n2 = v2 * inv * sc2;
  dst[lane] = f2bf((n1 * c1 - n2 * s1) * outscale);
  dst[lane + 64] = f2bf((n2 * c2 + n1 * s2) * outscale);
}

// ---------------- V f32 -> V_T[bg][128][S] bf16 ----------------
__global__ __launch_bounds__(256) void v_trans_kernel(
    const float* __restrict__ QKV, uint16_t* __restrict__ Vt) {
  __shared__ uint16_t T[128][72];
  const int s0 = blockIdx.x * 64;
  const int bg = blockIdx.y;
  const int b = bg >> 3, g = bg & 7;
  const int tid = threadIdx.x;
  const int tc = tid & 127, tr = tid >> 7;
  const float* src = QKV + ((size_t)(b * S_LEN + s0)) * 4096 + 3072 + g * 128;
  #pragma unroll
  for (int i = 0; i < 32; ++i) {
    int r = i * 2 + tr;
    T[tc][r] = f2bf(src[(size_t)r * 4096 + tc]);
  }
  __syncthreads();
  uint16_t* dst = Vt + (size_t)bg * 128 * S_LEN + s0;
  #pragma unroll
  for (int i = 0; i < 32; ++i) {
    int idx = i * 256 + tid;
    int d = idx >> 6, sof = idx & 63;
    dst[(size_t)d * S_LEN + sof] = T[d][sof];
  }
}

// ---------------- flash attention (round-2 structure, unchanged) ----------------
__global__ __launch_bounds__(256) void attn_kernel(
    const uint16_t* __restrict__ Qb, const uint16_t* __restrict__ Kb,
    const uint16_t* __restrict__ Vt, uint16_t* __restrict__ Ctx) {
  __shared__ uint8_t smem[65536 + 4 * 2304];
  const int tid = threadIdx.x, lane = tid & 63, wid = tid >> 6;
  uint16_t* Ps = (uint16_t*)(smem + 65536) + wid * 1152;  // [16][72] per wave
  const int l15 = lane & 15, l4 = lane >> 4;

  const int bh = blockIdx.y;
  const int b = bh >> 4, h = bh & 15;
  const int bg = b * NG + (h >> 1);  // GS = 2

  const uint16_t* Qh = Qb + (size_t)bh * S_LEN * HDIM;
  const uint16_t* Kh = Kb + (size_t)bg * S_LEN * HDIM;
  const uint16_t* Vh = Vt + (size_t)bg * HDIM * S_LEN;

  const int k_row = lane >> 4, k_c = lane & 15;  // K chunk: 4 rows x 256B
  const int v_row = lane >> 3, v_c = lane & 7;   // V chunk: 8 rows x 128B

#define STAGE(kt_, buf_)                                                      \
  do {                                                                        \
    const int kv0_ = (kt_) * 64;                                              \
    uint16_t* KsB_ = (uint16_t*)(smem + (buf_) * 16384);                      \
    uint16_t* VsB_ = (uint16_t*)(smem + 32768 + (buf_) * 16384);              \
    _Pragma("unroll")                                                         \
    for (int i_ = 0; i_ < 4; ++i_) {                                          \
      int chunk_ = wid * 4 + i_;                                              \
      int row_ = chunk_ * 4 + k_row;                                          \
      int sc_ = (k_c ^ (row_ & 7)) * 8;                                       \
      gload16(Kh + (size_t)(kv0_ + row_) * HDIM + sc_, KsB_ + chunk_ * 512);  \
    }                                                                         \
    _Pragma("unroll")                                                         \
    for (int i_ = 0; i_ < 4; ++i_) {                                          \
      int chunk_ = wid * 4 + i_;                                              \
      int row_ = chunk_ * 8 + v_row;                                          \
      int sc_ = (v_c ^ (row_ & 7)) * 8;                                       \
      gload16(Vh + (size_t)row_ * S_LEN + kv0_ + sc_, VsB_ + chunk_ * 512);   \
    }                                                                         \
  } while (0)

  for (int half = 0; half < 2; ++half) {
    const int qtile = half ? (31 - (int)blockIdx.x) : (int)blockIdx.x;
    const int q0 = qtile * 64;
    const int qrow = q0 + wid * 16 + l15;

    bf16x8 qf[4];
    #pragma unroll
    for (int kk = 0; kk < 4; ++kk)
      qf[kk] = *(const bf16x8*)(Qh + (size_t)qrow * HDIM + kk * 32 + l4 * 8);

    f32x4 acc[8];
    #pragma unroll
    for (int i = 0; i < 8; ++i) acc[i] = (f32x4){0.f, 0.f, 0.f, 0.f};
    float mrun = -1e30f, lrun = 0.f;

    const int nt = qtile + 1;
    int cur = 0;
    STAGE(0, 0);
    asm volatile("s_waitcnt vmcnt(0)\ns_barrier" ::: "memory");

    for (int kt = 0; kt < nt; ++kt) {
      const int kv0 = kt * 64;
      if (kt + 1 < nt) STAGE(kt + 1, cur ^ 1);

      uint16_t* Ks = (uint16_t*)(smem + cur * 16384);
      uint16_t* Vs = (uint16_t*)(smem + 32768 + cur * 16384);

      f32x4 sc[4];
      #pragma unroll
      for (int i = 0; i < 4; ++i) sc[i] = (f32x4){0.f, 0.f, 0.f, 0.f};
      __builtin_amdgcn_s_setprio(1);
      #pragma unroll
      for (int kk = 0; kk < 4; ++kk) {
        #pragma unroll
        for (int kc = 0; kc < 4; ++kc) {
          int key = kc * 16 + l15;
          int cc = (kk * 4 + l4) ^ (key & 7);
          bf16x8 kf = *(const bf16x8*)(Ks + key * 128 + cc * 8);
          sc[kc] = MFMA16(kf, qf[kk], sc[kc]);
        }
      }
      __builtin_amdgcn_s_setprio(0);
      if (kt == nt - 1) {
        #pragma unroll
        for (int kc = 0; kc < 4; ++kc)
          #pragma unroll
          for (int r = 0; r < 4; ++r)
            if (kv0 + kc * 16 + l4 * 4 + r > qrow) sc[kc][r] = -1e30f;
      }
      float tmax = -1e30f;
      #pragma unroll
      for (int kc = 0; kc < 4; ++kc)
        #pragma unroll
        for (int r = 0; r < 4; ++r) tmax = fmaxf(tmax, sc[kc][r]);
      tmax = fmaxf(tmax, __shfl_xor(tmax, 16));
      tmax = fmaxf(tmax, __shfl_xor(tmax, 32));
      float mnew = fmaxf(mrun, tmax);
      float corr = __expf(mrun - mnew);
      float tsum = 0.f;
      #pragma unroll
      for (int kc = 0; kc < 4; ++kc) {
        float p0 = __expf(sc[kc][0] - mnew);
        float p1 = __expf(sc[kc][1] - mnew);
        float p2 = __expf(sc[kc][2] - mnew);
        float p3 = __expf(sc[kc][3] - mnew);
        tsum += (p0 + p1) + (p2 + p3);
        ushort4 pw;
        pw.x = f2bf(p0); pw.y = f2bf(p1); pw.z = f2bf(p2); pw.w = f2bf(p3);
        *(ushort4*)(Ps + l15 * 72 + kc * 16 + l4 * 4) = pw;
      }
      tsum += __shfl_xor(tsum, 16);
      tsum += __shfl_xor(tsum, 32);
      lrun = lrun * corr + tsum;
      mrun = mnew;
      #pragma unroll
      for (int d0 = 0; d0 < 8; ++d0) acc[d0] *= corr;

      __builtin_amdgcn_s_setprio(1);
      #pragma unroll
      for (int hf = 0; hf < 2; ++hf) {
        bf16x8 pf = *(const bf16x8*)(Ps + l15 * 72 + hf * 32 + l4 * 8);
        #pragma unroll
        for (int d0 = 0; d0 < 8; ++d0) {
          int d = d0 * 16 + l15;
          int cc = (hf * 4 + l4) ^ (d & 7);
          bf16x8 vf = *(const bf16x8*)(Vs + d * 64 + cc * 8);
          acc[d0] = MFMA16(vf, pf, acc[d0]);
        }
      }
      __builtin_amdgcn_s_setprio(0);

      asm volatile("s_waitcnt vmcnt(0)\ns_barrier" ::: "memory");
      cur ^= 1;
    }

    float inv = 1.0f / lrun;
    uint16_t* dst = Ctx + ((size_t)(b * S_LEN + qrow) * NH + h) * HDIM;
    #pragma unroll
    for (int d0 = 0; d0 < 8; ++d0) {
      ushort4 o;
      o.x = f2bf(acc[d0][0] * inv);
      o.y = f2bf(acc[d0][1] * inv);
      o.z = f2bf(acc[d0][2] * inv);
      o.w = f2bf(acc[d0][3] * inv);
      *(ushort4*)(dst + d0 * 16 + l4 * 4) = o;
    }
  }
#undef STAGE
}

extern "C" void kernel_launch(void* const* d_in, const int* in_sizes, int n_in,
                              void* d_out, int out_size, void* d_ws, size_t ws_size,
                              hipStream_t stream) {
  const float* x    = (const float*)d_in[0];
  // d_in[1] = mask (unused; causal is known)
  const float* cosb = (const float*)d_in[2];
  const float* sinb = (const float*)d_in[3];
  const float* Wq   = (const float*)d_in[4];
  const float* Wk   = (const float*)d_in[5];
  const float* Wv   = (const float*)d_in[6];
  const float* Wo   = (const float*)d_in[7];
  const float* qs   = (const float*)d_in[8];
  const float* ks   = (const float*)d_in[9];

  char* ws = (char*)d_ws;
  uint16_t* Xb    = (uint16_t*)(ws);                         // 16 MB  [4096][2048]
  uint16_t* WallT = (uint16_t*)(ws + (16ull << 20));         // 16 MB  [4096][2048]
  uint16_t* WoT   = (uint16_t*)(ws + (32ull << 20));         //  8 MB  [2048][2048]
  float*    QKV   = (float*)   (ws + (40ull << 20));         // 64 MB  [4096][4096]
  uint16_t* Qb    = (uint16_t*)(ws + (104ull << 20));        // 16 MB  [B*H][S][128]
  uint16_t* Kb    = (uint16_t*)(ws + (120ull << 20));        //  8 MB  [B*G][S][128]
  uint16_t* Vt    = (uint16_t*)(ws + (128ull << 20));        //  8 MB  [B*G][128][S]
  uint16_t* Ctx   = (uint16_t*)(ws + (136ull << 20));        // 16 MB  [4096][2048]
  float* out = (float*)d_out;

  hipFuncSetAttribute(reinterpret_cast<const void*>(&gemm8p_kernel<256>),
                      hipFuncAttributeMaxDynamicSharedMemorySize, 131072);
  hipFuncSetAttribute(reinterpret_cast<const void*>(&gemm8p_kernel<128>),
                      hipFuncAttributeMaxDynamicSharedMemorySize, 98304);

  cvt_x_kernel<<<8192, 256, 0, stream>>>(x, Xb, 2097152);
  trans_cvt_kernel<<<dim3(64, 64), 256, 0, stream>>>(Wq, WallT, 2048, 2048);
  trans_cvt_kernel<<<dim3(32, 64), 256, 0, stream>>>(Wk, WallT + 2048 * 2048, 2048, 1024);
  trans_cvt_kernel<<<dim3(32, 64), 256, 0, stream>>>(Wv, WallT + 3072 * 2048, 2048, 1024);
  trans_cvt_kernel<<<dim3(64, 64), 256, 0, stream>>>(Wo, WoT, 2048, 2048);
  // QKV GEMM: M=4096 N=4096 K=2048, 256-wide tiles, 16x16 grid
  gemm8p_kernel<256><<<256, 512, 131072, stream>>>(Xb, WallT, QKV, 4096, 4096, 2048, 16);
  qk_rope_kernel<<<24576, 256, 0, stream>>>(QKV, cosb, sinb, qs, ks, Qb, Kb);
  v_trans_kernel<<<dim3(32, 16), 256, 0, stream>>>(QKV, Vt);
  attn_kernel<<<dim3(16, 32), 256, 0, stream>>>(Qb, Kb, Vt, Ctx);
  // Output GEMM: M=4096 N=2048 K=2048, BM=128 -> 32x8 = 256 blocks (full chip)
  gemm8p_kernel<128><<<256, 512, 98304, stream>>>(Ctx, WoT, out, 4096, 2048, 2048, 8);
}

// Round 4
// 341.767 us; speedup vs baseline: 1.3292x; 1.0483x over previous
//
#include <hip/hip_runtime.h>
#include <stdint.h>

#define S_LEN 2048
#define NH 16
#define NG 8
#define HDIM 128

typedef __bf16 bf16x8 __attribute__((ext_vector_type(8)));
typedef __bf16 bf16x4v __attribute__((ext_vector_type(4)));
typedef float f32x4 __attribute__((ext_vector_type(4)));

#define MFMA16(a, b, c) __builtin_amdgcn_mfma_f32_16x16x32_bf16((a), (b), (c), 0, 0, 0)

__device__ __forceinline__ uint16_t f2bf(float f) {
  union { float f; uint32_t u; } v; v.f = f;
  return (uint16_t)((v.u + 0x7fffu + ((v.u >> 16) & 1u)) >> 16);
}

__device__ __forceinline__ void gload16(const void* g, void* l) {
  __builtin_amdgcn_global_load_lds(
      (__attribute__((address_space(1))) const void*)g,
      (__attribute__((address_space(3))) void*)l, 16, 0, 0);
}

// ---------------- x -> bf16 ----------------
__global__ __launch_bounds__(256) void cvt_x_kernel(
    const float* __restrict__ x, uint16_t* __restrict__ xb, int n4) {
  int i = blockIdx.x * 256 + threadIdx.x;
  if (i >= n4) return;
  float4 v = ((const float4*)x)[i];
  ushort4 o;
  o.x = f2bf(v.x); o.y = f2bf(v.y); o.z = f2bf(v.z); o.w = f2bf(v.w);
  ((ushort4*)xb)[i] = o;
}

// ---------------- W[k][n] f32 -> dst[n][k] bf16 ----------------
__global__ __launch_bounds__(256) void trans_cvt_kernel(
    const float* __restrict__ src, uint16_t* __restrict__ dst, int K, int N) {
  __shared__ float T[32][33];
  int n0 = blockIdx.x * 32, k0 = blockIdx.y * 32;
  int tx = threadIdx.x & 31, ty = threadIdx.x >> 5;  // 32 x 8
  #pragma unroll
  for (int i = 0; i < 4; ++i)
    T[ty + i * 8][tx] = src[(size_t)(k0 + ty + i * 8) * N + n0 + tx];
  __syncthreads();
  #pragma unroll
  for (int i = 0; i < 4; ++i)
    dst[(size_t)(n0 + ty + i * 8) * K + k0 + tx] = f2bf(T[tx][ty + i * 8]);
}

// ================= 8-phase pipelined GEMM (T2+T3+T4+T5, derived waits) ======
template <int NISSUE>
__device__ __forceinline__ void stage_half(const uint16_t* __restrict__ g,
                                           int ldg, char* lds, int tid) {
  #pragma unroll
  for (int i = 0; i < NISSUE; ++i) {
    int ch = i * 512 + tid;
    int pair = ch >> 3, slotd = ch & 7;
    int slotl = slotd ^ (pair & 7);
    int row = pair * 2 + (slotl >> 2), c2 = slotl & 3;
    gload16(g + (size_t)row * ldg + c2 * 8, lds + ch * 16);
  }
}

__device__ __forceinline__ bf16x8 ldsfrag(const char* half_base, int row, int l4) {
  int pair = row >> 1;
  int slot = ((row & 1) << 2) | l4;
  return *(const bf16x8*)(half_base + pair * 128 + ((slot ^ (pair & 7)) * 16));
}

#define BAR() asm volatile("s_barrier" ::: "memory")

template <int BM>
__global__ __launch_bounds__(512, 2) void gemm8p_kernel(
    const uint16_t* __restrict__ A, const uint16_t* __restrict__ BT,
    float* __restrict__ C, int M, int N, int K, int gridN) {
  extern __shared__ char smem[];
  constexpr int MI = BM / 32;
  constexpr int LA = BM / 128;
  constexpr int ABYTES = BM * 64;
  const int tid = threadIdx.x, lane = tid & 63;
  const int wid = tid >> 6;
  const int l15 = lane & 15, l4 = lane >> 4;
  const int wm = wid >> 2, wn = wid & 3;

  const int nwg = gridDim.x, bid = blockIdx.x;
  const int cpx = nwg >> 3;
  const int swz = (bid & 7) * cpx + (bid >> 3);
  const int m0 = (swz / gridN) * BM, n0 = (swz % gridN) * 256;

  const uint16_t* Ag = A + (size_t)m0 * K;
  const uint16_t* Bg = BT + (size_t)n0 * K;
  const int NT = K >> 6;

#define ABASE(p, k) (smem + (((p) << 1) | (k)) * ABYTES)
#define BBASE(p, k) (smem + 4 * ABYTES + (((p) << 1) | (k)) * 16384)

  f32x4 acc[MI][4];
  #pragma unroll
  for (int mi = 0; mi < MI; ++mi)
    #pragma unroll
    for (int ni = 0; ni < 4; ++ni) acc[mi][ni] = (f32x4){0.f, 0.f, 0.f, 0.f};

  stage_half<LA>(Ag, K, ABASE(0, 0), tid);
  stage_half<2>(Bg, K, BBASE(0, 0), tid);
  stage_half<LA>(Ag + 32, K, ABASE(0, 1), tid);
  stage_half<2>(Bg + 32, K, BBASE(0, 1), tid);
  stage_half<LA>(Ag + 64, K, ABASE(1, 0), tid);
  stage_half<2>(Bg + 64, K, BBASE(1, 0), tid);
  if constexpr (BM == 256) asm volatile("s_waitcnt vmcnt(4)" ::: "memory");
  else                     asm volatile("s_waitcnt vmcnt(3)" ::: "memory");
  BAR();

  int par = 0;
  const int arow = wm * (BM / 2) + l15;
  for (int u = 0; u < NT; ++u, par ^= 1) {
    const int k0 = u * 64;
    bf16x8 af[MI], bf0, bf1;
    // ---- phase 0: (kh=0, nh=0) ----
    #pragma unroll
    for (int mi = 0; mi < MI; ++mi) af[mi] = ldsfrag(ABASE(par, 0), arow + mi * 16, l4);
    bf0 = ldsfrag(BBASE(par, 0), wn * 64 + l15, l4);
    bf1 = ldsfrag(BBASE(par, 0), wn * 64 + 16 + l15, l4);
    if (u + 1 < NT) stage_half<LA>(Ag + (k0 + 96), K, ABASE(par ^ 1, 1), tid);
    BAR();
    __builtin_amdgcn_s_setprio(1);
    #pragma unroll
    for (int mi = 0; mi < MI; ++mi) {
      acc[mi][0] = MFMA16(af[mi], bf0, acc[mi][0]);
      acc[mi][1] = MFMA16(af[mi], bf1, acc[mi][1]);
    }
    __builtin_amdgcn_s_setprio(0);
    BAR();
    // ---- phase 1: (kh=0, nh=1) ----
    bf0 = ldsfrag(BBASE(par, 0), wn * 64 + 32 + l15, l4);
    bf1 = ldsfrag(BBASE(par, 0), wn * 64 + 48 + l15, l4);
    if (u + 1 < NT) stage_half<2>(Bg + (k0 + 96), K, BBASE(par ^ 1, 1), tid);
    BAR();
    __builtin_amdgcn_s_setprio(1);
    #pragma unroll
    for (int mi = 0; mi < MI; ++mi) {
      acc[mi][2] = MFMA16(af[mi], bf0, acc[mi][2]);
      acc[mi][3] = MFMA16(af[mi], bf1, acc[mi][3]);
    }
    __builtin_amdgcn_s_setprio(0);
    BAR();
    // ---- phase 2: (kh=1, nh=1) ----
    #pragma unroll
    for (int mi = 0; mi < MI; ++mi) af[mi] = ldsfrag(ABASE(par, 1), arow + mi * 16, l4);
    bf0 = ldsfrag(BBASE(par, 1), wn * 64 + 32 + l15, l4);
    bf1 = ldsfrag(BBASE(par, 1), wn * 64 + 48 + l15, l4);
    if (u + 2 < NT) stage_half<LA>(Ag + (k0 + 128), K, ABASE(par, 0), tid);
    BAR();
    __builtin_amdgcn_s_setprio(1);
    #pragma unroll
    for (int mi = 0; mi < MI; ++mi) {
      acc[mi][2] = MFMA16(af[mi], bf0, acc[mi][2]);
      acc[mi][3] = MFMA16(af[mi], bf1, acc[mi][3]);
    }
    __builtin_amdgcn_s_setprio(0);
    BAR();
    // ---- phase 3: (kh=1, nh=0) ----
    bf0 = ldsfrag(BBASE(par, 1), wn * 64 + l15, l4);
    bf1 = ldsfrag(BBASE(par, 1), wn * 64 + 16 + l15, l4);
    if (u + 2 < NT) stage_half<2>(Bg + (k0 + 128), K, BBASE(par, 0), tid);
    BAR();
    __builtin_amdgcn_s_setprio(1);
    #pragma unroll
    for (int mi = 0; mi < MI; ++mi) {
      acc[mi][0] = MFMA16(af[mi], bf0, acc[mi][0]);
      acc[mi][1] = MFMA16(af[mi], bf1, acc[mi][1]);
    }
    __builtin_amdgcn_s_setprio(0);
    if (u + 2 < NT) {
      if constexpr (BM == 256) asm volatile("s_waitcnt vmcnt(4)" ::: "memory");
      else                     asm volatile("s_waitcnt vmcnt(3)" ::: "memory");
    } else {
      asm volatile("s_waitcnt vmcnt(0)" ::: "memory");
    }
    BAR();
  }

  #pragma unroll
  for (int mi = 0; mi < MI; ++mi)
    #pragma unroll
    for (int ni = 0; ni < 4; ++ni) {
      float* dst = C + (size_t)(m0 + wm * (BM / 2) + mi * 16 + l4 * 4) * N +
                   n0 + wn * 64 + ni * 16 + l15;
      #pragma unroll
      for (int r = 0; r < 4; ++r) dst[(size_t)r * N] = acc[mi][ni][r];
    }
#undef ABASE
#undef BBASE
}

// ---------------- RMSNorm + RoPE for Q and K (wave per row-head) ----------------
__global__ __launch_bounds__(256) void qk_rope_kernel(
    const float* __restrict__ QKV, const float* __restrict__ cosb,
    const float* __restrict__ sinb, const float* __restrict__ qs,
    const float* __restrict__ ks, uint16_t* __restrict__ Qb,
    uint16_t* __restrict__ Kb) {
  const int task = blockIdx.x * 4 + (threadIdx.x >> 6);
  const int lane = threadIdx.x & 63;
  const int hh = task % 24;
  const int row = task / 24;
  const int s = row & (S_LEN - 1);
  const int b = row >> 11;
  const float c1 = cosb[s * 128 + lane], c2 = cosb[s * 128 + 64 + lane];
  const float s1 = sinb[s * 128 + lane], s2 = sinb[s * 128 + 64 + lane];
  const float* src = QKV + (size_t)row * 4096;
  float v1, v2, sc1, sc2, outscale;
  uint16_t* dst;
  if (hh < 16) {
    v1 = src[hh * 128 + lane]; v2 = src[hh * 128 + 64 + lane];
    sc1 = qs[lane]; sc2 = qs[lane + 64];
    outscale = 0.088388347648318447f;  // 1/sqrt(HD), folded softmax scale
    dst = Qb + ((size_t)(b * NH + hh) * S_LEN + s) * 128;
  } else {
    int g = hh - 16;
    v1 = src[2048 + g * 128 + lane]; v2 = src[2048 + g * 128 + 64 + lane];
    sc1 = ks[lane]; sc2 = ks[lane + 64];
    outscale = 1.0f;
    dst = Kb + ((size_t)(b * NG + g) * S_LEN + s) * 128;
  }
  float ss = v1 * v1 + v2 * v2;
  #pragma unroll
  for (int o = 1; o < 64; o <<= 1) ss += __shfl_xor(ss, o);
  float inv = rsqrtf(ss * (1.0f / 128.0f) + 1e-6f);
  float n1 = v1 * inv * sc1, n2 = v2 * inv * sc2;
  dst[lane] = f2bf((n1 * c1 - n2 * s1) * outscale);
  dst[lane + 64] = f2bf((n2 * c2 + n1 * s2) * outscale);
}

// ---------------- V f32 -> V_T[bg][128][S] bf16 ----------------
__global__ __launch_bounds__(256) void v_trans_kernel(
    const float* __restrict__ QKV, uint16_t* __restrict__ Vt) {
  __shared__ uint16_t T[128][72];
  const int s0 = blockIdx.x * 64;
  const int bg = blockIdx.y;
  const int b = bg >> 3, g = bg & 7;
  const int tid = threadIdx.x;
  const int tc = tid & 127, tr = tid >> 7;
  const float* src = QKV + ((size_t)(b * S_LEN + s0)) * 4096 + 3072 + g * 128;
  #pragma unroll
  for (int i = 0; i < 32; ++i) {
    int r = i * 2 + tr;
    T[tc][r] = f2bf(src[(size_t)r * 4096 + tc]);
  }
  __syncthreads();
  uint16_t* dst = Vt + (size_t)bg * 128 * S_LEN + s0;
  #pragma unroll
  for (int i = 0; i < 32; ++i) {
    int idx = i * 256 + tid;
    int d = idx >> 6, sof = idx & 63;
    dst[(size_t)d * S_LEN + sof] = T[d][sof];
  }
}

// ---------------- flash attention ----------------
// GQA head-sharing: block = (b,g); 8 waves = 2 heads x 4 waves x 16 q-rows.
// K/V tile staged ONCE serves both heads. Paired q-tiles {x, 31-x} keep all
// blocks at 33 KV-steps. grid (16,16)=256 blocks = 1/CU, 8 waves = 2/SIMD.
// Double-buffered LDS, one vmcnt(0)+barrier per step. T13 defer-max skips
// the O-rescale unless the tile max grows by >8.
__global__ __launch_bounds__(512) void attn_kernel(
    const uint16_t* __restrict__ Qb, const uint16_t* __restrict__ Kb,
    const uint16_t* __restrict__ Vt, uint16_t* __restrict__ Ctx) {
  __shared__ uint8_t smem[65536 + 8 * 2304];
  const int tid = threadIdx.x, lane = tid & 63, wid = tid >> 6;
  uint16_t* Ps = (uint16_t*)(smem + 65536) + wid * 1152;  // [16][72] per wave
  const int l15 = lane & 15, l4 = lane >> 4;

  const int bg = blockIdx.y;           // b*8 + g
  const int b = bg >> 3, g = bg & 7;
  const int h = (g << 1) | (wid >> 2); // wave's head within the group
  const int bh = b * NH + h;

  const uint16_t* Qh = Qb + (size_t)bh * S_LEN * HDIM;
  const uint16_t* Kh = Kb + (size_t)bg * S_LEN * HDIM;
  const uint16_t* Vh = Vt + (size_t)bg * HDIM * S_LEN;

  const int k_row = lane >> 4, k_c = lane & 15;  // K chunk: 4 rows x 256B
  const int v_row = lane >> 3, v_c = lane & 7;   // V chunk: 8 rows x 128B

// 16 K-chunks + 16 V-chunks over 8 waves -> 2+2 gloads per wave
#define STAGE(kt_, buf_)                                                      \
  do {                                                                        \
    const int kv0_ = (kt_) * 64;                                              \
    uint16_t* KsB_ = (uint16_t*)(smem + (buf_) * 16384);                      \
    uint16_t* VsB_ = (uint16_t*)(smem + 32768 + (buf_) * 16384);              \
    _Pragma("unroll")                                                         \
    for (int i_ = 0; i_ < 2; ++i_) {                                          \
      int chunk_ = wid * 2 + i_;                                              \
      int row_ = chunk_ * 4 + k_row;                                          \
      int sc_ = (k_c ^ (row_ & 7)) * 8;                                       \
      gload16(Kh + (size_t)(kv0_ + row_) * HDIM + sc_, KsB_ + chunk_ * 512);  \
    }                                                                         \
    _Pragma("unroll")                                                         \
    for (int i_ = 0; i_ < 2; ++i_) {                                          \
      int chunk_ = wid * 2 + i_;                                              \
      int row_ = chunk_ * 8 + v_row;                                          \
      int sc_ = (v_c ^ (row_ & 7)) * 8;                                       \
      gload16(Vh + (size_t)row_ * S_LEN + kv0_ + sc_, VsB_ + chunk_ * 512);   \
    }                                                                         \
  } while (0)

  for (int half = 0; half < 2; ++half) {
    const int qtile = half ? (31 - (int)blockIdx.x) : (int)blockIdx.x;
    const int q0 = qtile * 64;
    const int qrow = q0 + (wid & 3) * 16 + l15;

    bf16x8 qf[4];
    #pragma unroll
    for (int kk = 0; kk < 4; ++kk)
      qf[kk] = *(const bf16x8*)(Qh + (size_t)qrow * HDIM + kk * 32 + l4 * 8);

    f32x4 acc[8];
    #pragma unroll
    for (int i = 0; i < 8; ++i) acc[i] = (f32x4){0.f, 0.f, 0.f, 0.f};
    float mrun = -1e30f, lrun = 0.f;

    const int nt = qtile + 1;
    int cur = 0;
    STAGE(0, 0);
    asm volatile("s_waitcnt vmcnt(0)\ns_barrier" ::: "memory");

    for (int kt = 0; kt < nt; ++kt) {
      const int kv0 = kt * 64;
      if (kt + 1 < nt) STAGE(kt + 1, cur ^ 1);

      uint16_t* Ks = (uint16_t*)(smem + cur * 16384);
      uint16_t* Vs = (uint16_t*)(smem + 32768 + cur * 16384);

      // S^T[key][qrow] = K @ Q^T (lane owns q-row = l15)
      f32x4 sc[4];
      #pragma unroll
      for (int i = 0; i < 4; ++i) sc[i] = (f32x4){0.f, 0.f, 0.f, 0.f};
      __builtin_amdgcn_s_setprio(1);
      #pragma unroll
      for (int kk = 0; kk < 4; ++kk) {
        #pragma unroll
        for (int kc = 0; kc < 4; ++kc) {
          int key = kc * 16 + l15;
          int cc = (kk * 4 + l4) ^ (key & 7);
          bf16x8 kf = *(const bf16x8*)(Ks + key * 128 + cc * 8);
          sc[kc] = MFMA16(kf, qf[kk], sc[kc]);
        }
      }
      __builtin_amdgcn_s_setprio(0);
      if (kt == nt - 1) {  // diagonal tile: causal mask
        #pragma unroll
        for (int kc = 0; kc < 4; ++kc)
          #pragma unroll
          for (int r = 0; r < 4; ++r)
            if (kv0 + kc * 16 + l4 * 4 + r > qrow) sc[kc][r] = -1e30f;
      }
      float tmax = -1e30f;
      #pragma unroll
      for (int kc = 0; kc < 4; ++kc)
        #pragma unroll
        for (int r = 0; r < 4; ++r) tmax = fmaxf(tmax, sc[kc][r]);
      tmax = fmaxf(tmax, __shfl_xor(tmax, 16));
      tmax = fmaxf(tmax, __shfl_xor(tmax, 32));
      // T13 defer-max: only rescale when the max actually grows by >8
      if (!__all(tmax <= mrun + 8.0f)) {
        float mnew = fmaxf(mrun, tmax);
        float corr = __expf(mrun - mnew);
        lrun *= corr;
        #pragma unroll
        for (int d0 = 0; d0 < 8; ++d0) acc[d0] *= corr;
        mrun = mnew;
      }
      float tsum = 0.f;
      #pragma unroll
      for (int kc = 0; kc < 4; ++kc) {
        float p0 = __expf(sc[kc][0] - mrun);
        float p1 = __expf(sc[kc][1] - mrun);
        float p2 = __expf(sc[kc][2] - mrun);
        float p3 = __expf(sc[kc][3] - mrun);
        tsum += (p0 + p1) + (p2 + p3);
        bf16x4v pw = {(__bf16)p0, (__bf16)p1, (__bf16)p2, (__bf16)p3};
        *(bf16x4v*)(Ps + l15 * 72 + kc * 16 + l4 * 4) = pw;
      }
      tsum += __shfl_xor(tsum, 16);
      tsum += __shfl_xor(tsum, 32);
      lrun += tsum;

      // ctx^T[d][qrow] += V^T @ P^T
      __builtin_amdgcn_s_setprio(1);
      #pragma unroll
      for (int hf = 0; hf < 2; ++hf) {
        bf16x8 pf = *(const bf16x8*)(Ps + l15 * 72 + hf * 32 + l4 * 8);
        #pragma unroll
        for (int d0 = 0; d0 < 8; ++d0) {
          int d = d0 * 16 + l15;
          int cc = (hf * 4 + l4) ^ (d & 7);
          bf16x8 vf = *(const bf16x8*)(Vs + d * 64 + cc * 8);
          acc[d0] = MFMA16(vf, pf, acc[d0]);
        }
      }
      __builtin_amdgcn_s_setprio(0);

      asm volatile("s_waitcnt vmcnt(0)\ns_barrier" ::: "memory");
      cur ^= 1;
    }

    float inv = 1.0f / lrun;
    uint16_t* dst = Ctx + ((size_t)(b * S_LEN + qrow) * NH + h) * HDIM;
    #pragma unroll
    for (int d0 = 0; d0 < 8; ++d0) {
      bf16x4v o = {(__bf16)(acc[d0][0] * inv), (__bf16)(acc[d0][1] * inv),
                   (__bf16)(acc[d0][2] * inv), (__bf16)(acc[d0][3] * inv)};
      *(bf16x4v*)(dst + d0 * 16 + l4 * 4) = o;
    }
  }
#undef STAGE
}

extern "C" void kernel_launch(void* const* d_in, const int* in_sizes, int n_in,
                              void* d_out, int out_size, void* d_ws, size_t ws_size,
                              hipStream_t stream) {
  const float* x    = (const float*)d_in[0];
  const float* cosb = (const float*)d_in[2];
  const float* sinb = (const float*)d_in[3];
  const float* Wq   = (const float*)d_in[4];
  const float* Wk   = (const float*)d_in[5];
  const float* Wv   = (const float*)d_in[6];
  const float* Wo   = (const float*)d_in[7];
  const float* qs   = (const float*)d_in[8];
  const float* ks   = (const float*)d_in[9];

  char* ws = (char*)d_ws;
  uint16_t* Xb    = (uint16_t*)(ws);                         // 16 MB  [4096][2048]
  uint16_t* WallT = (uint16_t*)(ws + (16ull << 20));         // 16 MB  [4096][2048]
  uint16_t* WoT   = (uint16_t*)(ws + (32ull << 20));         //  8 MB  [2048][2048]
  float*    QKV   = (float*)   (ws + (40ull << 20));         // 64 MB  [4096][4096]
  uint16_t* Qb    = (uint16_t*)(ws + (104ull << 20));        // 16 MB  [B*H][S][128]
  uint16_t* Kb    = (uint16_t*)(ws + (120ull << 20));        //  8 MB  [B*G][S][128]
  uint16_t* Vt    = (uint16_t*)(ws + (128ull << 20));        //  8 MB  [B*G][128][S]
  uint16_t* Ctx   = (uint16_t*)(ws + (136ull << 20));        // 16 MB  [4096][2048]
  float* out = (float*)d_out;

  hipFuncSetAttribute(reinterpret_cast<const void*>(&gemm8p_kernel<256>),
                      hipFuncAttributeMaxDynamicSharedMemorySize, 131072);
  hipFuncSetAttribute(reinterpret_cast<const void*>(&gemm8p_kernel<128>),
                      hipFuncAttributeMaxDynamicSharedMemorySize, 98304);

  cvt_x_kernel<<<8192, 256, 0, stream>>>(x, Xb, 2097152);
  trans_cvt_kernel<<<dim3(64, 64), 256, 0, stream>>>(Wq, WallT, 2048, 2048);
  trans_cvt_kernel<<<dim3(32, 64), 256, 0, stream>>>(Wk, WallT + 2048 * 2048, 2048, 1024);
  trans_cvt_kernel<<<dim3(32, 64), 256, 0, stream>>>(Wv, WallT + 3072 * 2048, 2048, 1024);
  trans_cvt_kernel<<<dim3(64, 64), 256, 0, stream>>>(Wo, WoT, 2048, 2048);
  gemm8p_kernel<256><<<256, 512, 131072, stream>>>(Xb, WallT, QKV, 4096, 4096, 2048, 16);
  qk_rope_kernel<<<24576, 256, 0, stream>>>(QKV, cosb, sinb, qs, ks, Qb, Kb);
  v_trans_kernel<<<dim3(32, 16), 256, 0, stream>>>(QKV, Vt);
  attn_kernel<<<dim3(16, 16), 512, 0, stream>>>(Qb, Kb, Vt, Ctx);
  gemm8p_kernel<128><<<256, 512, 98304, stream>>>(Ctx, WoT, out, 4096, 2048, 2048, 8);
}